// Round 6
// baseline (280.030 us; speedup 1.0000x reference)
//
#include <hip/hip_runtime.h>
#include <math.h>

#define NN     16384
#define EE     600000
#define HIDN   128
#define NFT    32
#define NGAUSS 50
#define NLAY   6
#define TABN   8192
#define CUTF   10.0f

typedef float f32x4  __attribute__((ext_vector_type(4)));
typedef short bf16x8 __attribute__((ext_vector_type(8)));

__device__ __forceinline__ float ssp(float x) {
    // softplus(x) - log(2), numerically stable
    return fmaxf(x, 0.0f) + log1pf(__expf(-fabsf(x))) - 0.69314718055994531f;
}

__device__ __forceinline__ short f2bf(float x) {
    // f32 -> bf16 round-to-nearest-even
    union { float f; unsigned u; } v; v.f = x;
    unsigned r = v.u + 0x7fffu + ((v.u >> 16) & 1u);
    return (short)(r >> 16);
}

// ---------------------------------------------------------------- row_ptr ---
// Real edges (mask>0.5) are a prefix with dst ascending; padding after.
// key(e) = real ? dst[e] : INT_MAX is monotone -> per-thread lower_bound.
__global__ void build_rowptr(const int* __restrict__ dst, const float* __restrict__ mask,
                             int* __restrict__ rp) {
    int n = blockIdx.x * blockDim.x + threadIdx.x;
    if (n > NN) return;
    int lo = 0, hi = EE;
    while (lo < hi) {
        int mid = (lo + hi) >> 1;
        int key = (mask[mid] > 0.5f) ? dst[mid] : 0x7fffffff;
        if (key < n) lo = mid + 1; else hi = mid;
    }
    rp[n] = lo;
}

// ------------------------------------------------------------- edge geom ----
// geo[e] = (d * TABSCALE, cutoff_coeff)
__global__ void edge_geom(const int* __restrict__ ei, const float* __restrict__ pos,
                          const float* __restrict__ mask, float2* __restrict__ geo) {
    int e = blockIdx.x * blockDim.x + threadIdx.x;
    if (e >= EE) return;
    int s = ei[e], t = ei[EE + e];
    float dx = pos[s * 3 + 0] - pos[t * 3 + 0];
    float dy = pos[s * 3 + 1] - pos[t * 3 + 1];
    float dz = pos[s * 3 + 2] - pos[t * 3 + 2];
    float d = sqrtf(dx * dx + dy * dy + dz * dz);
    float cc = 0.5f * (cosf(d * 0.31415926535897932f) + 1.0f) * mask[e];
    geo[e] = make_float2(d * ((TABN - 1) / CUTF), cc);
}

// ----------------------------------------------------------- table build ----
__global__ void tab_kernel(const float* __restrict__ w1, const float* __restrict__ b1,
                           const float* __restrict__ w2, const float* __restrict__ b2,
                           float* __restrict__ tab) {
    __shared__ float ea[8][NGAUSS];
    __shared__ float t1[8][NFT];
    int t = threadIdx.x, f = t & 31, g = t >> 5;
    int id = blockIdx.x * 8 + g;           // 0 .. NLAY*TABN-1 exact
    int l = id / TABN, ent = id % TABN;
    float d = ent * (CUTF / (TABN - 1));
    const float delta = CUTF / (NGAUSS - 1);
    const float coeff = -0.5f / (delta * delta);
    for (int gg = f; gg < NGAUSS; gg += 32) {
        float diff = d - gg * delta;
        ea[g][gg] = __expf(coeff * diff * diff);
    }
    __syncthreads();
    float a = b1[l * NFT + f];
    const float* w1l = w1 + l * NGAUSS * NFT;
    #pragma unroll
    for (int gg = 0; gg < NGAUSS; ++gg)
        a = fmaf(ea[g][gg], w1l[gg * NFT + f], a);
    t1[g][f] = ssp(a);
    __syncthreads();
    float c = b2[l * NFT + f];
    const float* w2l = w2 + l * NFT * NFT;
    #pragma unroll
    for (int k = 0; k < NFT; ++k)
        c = fmaf(t1[g][k], w2l[k * NFT + f], c);
    tab[(size_t)id * NFT + f] = c;
}

// ---------------------------------------------------------------- init h ----
__global__ void init_h(const int* __restrict__ z, const float4* __restrict__ emb4,
                       float4* __restrict__ h4) {
    int tid = blockIdx.x * blockDim.x + threadIdx.x;   // N*32 threads
    int n = tid >> 5, c = tid & 31;
    h4[tid] = emb4[(size_t)z[n] * 32 + c];
}

// --------------------------------------------------------- weight prep ------
//  l2wT[l][f<128][k<32]  = l2w[l][k][f]
//  lwT [l][f<128][k<128] = lw [l][k][f]
//  l1T [l][f<32 ][k<128] = l1 [l][k][f]
__global__ void prep_weights(const float* __restrict__ l2w, const float* __restrict__ lww,
                             const float* __restrict__ l1w,
                             short* __restrict__ l2wT, short* __restrict__ lwT,
                             short* __restrict__ l1T) {
    const int per = 4096 + 16384 + 4096;   // 24576 per layer
    int id = blockIdx.x * blockDim.x + threadIdx.x;
    if (id >= NLAY * per) return;
    int l = id / per, r = id % per;
    if (r < 4096) {
        int f = r >> 5, k = r & 31;
        l2wT[l * 4096 + f * 32 + k] = f2bf(l2w[l * 4096 + k * 128 + f]);
    } else if (r < 4096 + 16384) {
        int q = r - 4096; int f = q >> 7, k = q & 127;
        lwT[l * 16384 + f * 128 + k] = f2bf(lww[l * 16384 + k * 128 + f]);
    } else {
        int q = r - 20480; int f = q >> 7, k = q & 127;   // f<32, k<128
        l1T[l * 4096 + f * 128 + k] = f2bf(l1w[l * 4096 + k * 32 + f]);
    }
}

// ------------------------------------------------- hw = h@l1 (layer 0) ------
__global__ void hw_kernel(const float* __restrict__ h, const float* __restrict__ l1,
                          float* __restrict__ hw) {
    __shared__ float l1s[HIDN * NFT];
    int t = threadIdx.x, f = t & 31, nl = t >> 5;
    for (int i = t; i < HIDN * NFT / 4; i += 256)
        ((float4*)l1s)[i] = ((const float4*)l1)[i];
    __syncthreads();
    int n = blockIdx.x * 8 + nl;
    const float4* h4 = (const float4*)(h + (size_t)n * HIDN);
    float acc = 0.0f;
    #pragma unroll
    for (int k4 = 0; k4 < 32; ++k4) {
        float4 hv = h4[k4];
        acc = fmaf(hv.x, l1s[(k4 * 4 + 0) * NFT + f], acc);
        acc = fmaf(hv.y, l1s[(k4 * 4 + 1) * NFT + f], acc);
        acc = fmaf(hv.z, l1s[(k4 * 4 + 2) * NFT + f], acc);
        acc = fmaf(hv.w, l1s[(k4 * 4 + 3) * NFT + f], acc);
    }
    hw[(size_t)n * NFT + f] = acc;
}

// ================== fused layer: edge aggregate + node update ==============
// Per block (16 nodes, 256 thr = 4 waves):
//   1) m[n] = sum_e hw[src]*W(d)*cc   (CSR rows are block-local -> no sync)
//   2) x = ssp(m@l2w+l2b); h += x@lw+lb; hw_next = h_new@l1[l+1]  (MFMA)
// hw is ping-ponged across layers (phase-C write vs other blocks' phase-1
// read would otherwise race).
// mfma_f32_16x16x32_bf16 layouts (m89/m91-verified):
//   A: lane(16g+r) holds A[r][8g..8g+7];  B: lane(16g+c) holds B[8g..8g+7][c]
//   C/D: col = lane&15, row = 4*(lane>>4) + reg
// xs/hs XOR-swizzled (G4); m_lds padded to 36 floats/row (2-way max = free).
#define EDGE_BODY(EIDX)                                                    \
    {                                                                      \
        int e_ = (EIDX);                                                   \
        int s_ = src[e_];                                                  \
        float2 g_ = geo[e_];                                               \
        float p_ = g_.x;                                                   \
        int i0_ = (int)p_;                                                 \
        i0_ = (i0_ > TABN - 2) ? (TABN - 2) : i0_;                         \
        float fr_ = p_ - (float)i0_;                                       \
        float w0_ = tabL[(size_t)i0_ * NFT + f];                           \
        float w1_ = tabL[(size_t)i0_ * NFT + NFT + f];                     \
        float w_ = fmaf(fr_, w1_ - w0_, w0_);                              \
        acc = fmaf(hwin[(size_t)s_ * NFT + f], w_ * g_.y, acc);            \
    }

__global__ __launch_bounds__(256, 4) void fused_layer(
        const int* __restrict__ rp, const int* __restrict__ src,
        const float2* __restrict__ geo, const float* __restrict__ tabL,
        const float* __restrict__ hwin,
        const short* __restrict__ l2wT, const float* __restrict__ l2b,
        const short* __restrict__ lwT, const float* __restrict__ lb,
        float* __restrict__ h,
        const short* __restrict__ l1Tn, float* __restrict__ hwout) {
    __shared__ float m_lds[16][36];         // padded: bank-friendly b128 reads
    __shared__ short xs[16 * 128];          // 4 KB bf16, swizzled
    __shared__ short hs[16 * 128];          // 4 KB bf16, swizzled
    const int t   = threadIdx.x;
    const int w   = t >> 6;                 // wave 0..3
    const int l   = t & 63;
    const int lr  = l & 15;
    const int lg  = l >> 4;                 // k-group 0..3
    const int f   = l & 31;                 // feature lane (edge phase)
    const int par = l >> 5;                 // edge parity (edge phase)
    const int nb  = blockIdx.x << 4;        // 16 nodes per block
    const int ft0 = w * 2, ft1 = w * 2 + 1;

    // ---- issue-early: weights / biases / h-old for the MFMA phases
    bf16x8 aw0 = *(const bf16x8*)(l2wT + (ft0 * 16 + lr) * 32 + lg * 8);
    bf16x8 aw1 = *(const bf16x8*)(l2wT + (ft1 * 16 + lr) * 32 + lg * 8);
    bf16x8 bw0[4], bw1[4];
    #pragma unroll
    for (int ks = 0; ks < 4; ++ks) {
        bw0[ks] = *(const bf16x8*)(lwT + (ft0 * 16 + lr) * 128 + ks * 32 + lg * 8);
        bw1[ks] = *(const bf16x8*)(lwT + (ft1 * 16 + lr) * 128 + ks * 32 + lg * 8);
    }
    float biasA0 = l2b[ft0 * 16 + lr], biasA1 = l2b[ft1 * 16 + lr];
    float biasB0 = lb[ft0 * 16 + lr],  biasB1 = lb[ft1 * 16 + lr];
    float hold0[4], hold1[4];
    #pragma unroll
    for (int i = 0; i < 4; ++i) {
        hold0[i] = h[(size_t)(nb + lg * 4 + i) * HIDN + ft0 * 16 + lr];
        hold1[i] = h[(size_t)(nb + lg * 4 + i) * HIDN + ft1 * 16 + lr];
    }
    bf16x8 cw[4];
    if (l1Tn != nullptr && w < 2) {
        #pragma unroll
        for (int ks = 0; ks < 4; ++ks)
            cw[ks] = *(const bf16x8*)(l1Tn + (w * 16 + lr) * 128 + ks * 32 + lg * 8);
    }

    // ======== phase 1: edge aggregate, wave w owns nodes nb+4w..nb+4w+3 ====
    #pragma unroll
    for (int q = 0; q < 4; ++q) {
        int n = nb + w * 4 + q;
        int r0 = rp[n], r1 = rp[n + 1];
        float acc = 0.0f;
        int e = r0 + par;
        for (; e + 2 < r1; e += 4) {        // two independent bodies -> ILP
            EDGE_BODY(e);
            EDGE_BODY(e + 2);
        }
        if (e < r1) EDGE_BODY(e);
        acc += __shfl_xor(acc, 32);
        if (par == 0) m_lds[w * 4 + q][f] = acc;
    }
    __syncthreads();

    // ======== phase A: x = ssp(m @ l2w + l2b) ========
    bf16x8 ma;
    {
        f32x4 m0 = *(const f32x4*)(&m_lds[lr][lg * 8]);
        f32x4 m1 = *(const f32x4*)(&m_lds[lr][lg * 8 + 4]);
        ma[0] = f2bf(m0.x); ma[1] = f2bf(m0.y); ma[2] = f2bf(m0.z); ma[3] = f2bf(m0.w);
        ma[4] = f2bf(m1.x); ma[5] = f2bf(m1.y); ma[6] = f2bf(m1.z); ma[7] = f2bf(m1.w);
    }
    f32x4 cA0 = {0.f, 0.f, 0.f, 0.f}, cA1 = {0.f, 0.f, 0.f, 0.f};
    cA0 = __builtin_amdgcn_mfma_f32_16x16x32_bf16(ma, aw0, cA0, 0, 0, 0);
    cA1 = __builtin_amdgcn_mfma_f32_16x16x32_bf16(ma, aw1, cA1, 0, 0, 0);
    #pragma unroll
    for (int i = 0; i < 4; ++i) {
        int row = lg * 4 + i;
        int col0 = ft0 * 16 + lr;
        int col1 = ft1 * 16 + lr;
        xs[row * 128 + ((col0 >> 3) ^ (row & 7)) * 8 + (col0 & 7)] = f2bf(ssp(cA0[i] + biasA0));
        xs[row * 128 + ((col1 >> 3) ^ (row & 7)) * 8 + (col1 & 7)] = f2bf(ssp(cA1[i] + biasA1));
    }
    __syncthreads();

    // ======== phase B: h += x @ lw + lb  (K = 128) ========
    bf16x8 xa[4];
    #pragma unroll
    for (int ks = 0; ks < 4; ++ks)
        xa[ks] = *(const bf16x8*)(xs + lr * 128 + ((ks * 4 + lg) ^ (lr & 7)) * 8);
    f32x4 cB0 = {0.f, 0.f, 0.f, 0.f}, cB1 = {0.f, 0.f, 0.f, 0.f};
    #pragma unroll
    for (int ks = 0; ks < 4; ++ks)
        cB0 = __builtin_amdgcn_mfma_f32_16x16x32_bf16(xa[ks], bw0[ks], cB0, 0, 0, 0);
    #pragma unroll
    for (int ks = 0; ks < 4; ++ks)
        cB1 = __builtin_amdgcn_mfma_f32_16x16x32_bf16(xa[ks], bw1[ks], cB1, 0, 0, 0);
    #pragma unroll
    for (int i = 0; i < 4; ++i) {
        int node = nb + lg * 4 + i;
        int row = lg * 4 + i;
        float hv0 = hold0[i] + cB0[i] + biasB0;
        float hv1 = hold1[i] + cB1[i] + biasB1;
        h[(size_t)node * HIDN + ft0 * 16 + lr] = hv0;
        h[(size_t)node * HIDN + ft1 * 16 + lr] = hv1;
        int col0 = ft0 * 16 + lr;
        int col1 = ft1 * 16 + lr;
        hs[row * 128 + ((col0 >> 3) ^ (row & 7)) * 8 + (col0 & 7)] = f2bf(hv0);
        hs[row * 128 + ((col1 >> 3) ^ (row & 7)) * 8 + (col1 & 7)] = f2bf(hv1);
    }

    // ======== phase C: hw_next = h_new @ l1[l+1]  (ping-pong buffer) ========
    if (l1Tn != nullptr) {
        __syncthreads();
        if (w < 2) {
            bf16x8 ha[4];
            #pragma unroll
            for (int ks = 0; ks < 4; ++ks)
                ha[ks] = *(const bf16x8*)(hs + lr * 128 + ((ks * 4 + lg) ^ (lr & 7)) * 8);
            f32x4 c = {0.f, 0.f, 0.f, 0.f};
            #pragma unroll
            for (int ks = 0; ks < 4; ++ks)
                c = __builtin_amdgcn_mfma_f32_16x16x32_bf16(ha[ks], cw[ks], c, 0, 0, 0);
            #pragma unroll
            for (int i = 0; i < 4; ++i) {
                int node = nb + lg * 4 + i;
                hwout[(size_t)node * NFT + w * 16 + lr] = c[i];
            }
        }
    }
}

// ---------------------------------------------------------------------------
extern "C" void kernel_launch(void* const* d_in, const int* in_sizes, int n_in,
                              void* d_out, int out_size, void* d_ws, size_t ws_size,
                              hipStream_t stream) {
    const int*   z    = (const int*)d_in[0];
    const float* pos  = (const float*)d_in[1];
    const int*   ei   = (const int*)d_in[2];    // [2][E]
    const float* mask = (const float*)d_in[3];
    const float* emb  = (const float*)d_in[4];
    const float* w1   = (const float*)d_in[5];  // [6][50][32]
    const float* b1   = (const float*)d_in[6];  // [6][32]
    const float* w2   = (const float*)d_in[7];  // [6][32][32]
    const float* b2   = (const float*)d_in[8];  // [6][32]
    const float* l1w  = (const float*)d_in[9];  // [6][128][32]
    const float* l2w  = (const float*)d_in[10]; // [6][32][128]
    const float* l2b  = (const float*)d_in[11]; // [6][128]
    const float* lww  = (const float*)d_in[12]; // [6][128][128]
    const float* lbb  = (const float*)d_in[13]; // [6][128]
    float* h = (float*)d_out;

    char* base = (char*)d_ws;
    size_t o = 0;
    auto alloc = [&](size_t bytes) -> void* {
        void* p = base + o;
        o += (bytes + 255) & ~(size_t)255;
        return p;
    };
    int*    d_rp   = (int*)alloc((NN + 1) * sizeof(int));
    float2* d_geo  = (float2*)alloc((size_t)EE * sizeof(float2));
    float*  d_tab  = (float*)alloc((size_t)NLAY * TABN * NFT * sizeof(float));
    float*  d_hwA  = (float*)alloc((size_t)NN * NFT * sizeof(float));
    float*  d_hwB  = (float*)alloc((size_t)NN * NFT * sizeof(float));
    short*  d_l2wT = (short*)alloc((size_t)NLAY * 4096 * sizeof(short));
    short*  d_lwT  = (short*)alloc((size_t)NLAY * 16384 * sizeof(short));
    short*  d_l1T  = (short*)alloc((size_t)NLAY * 4096 * sizeof(short));
    (void)ws_size; (void)in_sizes; (void)n_in; (void)out_size;

    prep_weights<<<(NLAY * 24576 + 255) / 256, 256, 0, stream>>>(
        l2w, lww, l1w, d_l2wT, d_lwT, d_l1T);
    build_rowptr<<<(NN + 1 + 255) / 256, 256, 0, stream>>>(ei + EE, mask, d_rp);
    edge_geom<<<(EE + 255) / 256, 256, 0, stream>>>(ei, pos, mask, d_geo);
    tab_kernel<<<NLAY * TABN / 8, 256, 0, stream>>>(w1, b1, w2, b2, d_tab);
    init_h<<<NN * 32 / 256, 256, 0, stream>>>(z, (const float4*)emb, (float4*)h);
    hw_kernel<<<NN / 8, 256, 0, stream>>>(h, l1w, d_hwA);   // layer-0 hw (f32)

    for (int l = 0; l < NLAY; ++l) {
        const float* hwin  = (l & 1) ? d_hwB : d_hwA;
        float*       hwout = (l & 1) ? d_hwA : d_hwB;
        const short* l1Tn  = (l + 1 < NLAY) ? (d_l1T + (size_t)(l + 1) * 4096) : nullptr;
        fused_layer<<<NN / 16, 256, 0, stream>>>(
            d_rp, ei, d_geo, d_tab + (size_t)l * TABN * NFT, hwin,
            d_l2wT + (size_t)l * 4096, l2b + (size_t)l * HIDN,
            d_lwT + (size_t)l * 16384, lbb + (size_t)l * HIDN, h, l1Tn, hwout);
    }
}